// Round 2
// baseline (2439.684 us; speedup 1.0000x reference)
//
#include <hip/hip_runtime.h>
#include <math.h>

#define B_  4
#define N_  4096
#define D_  1024
#define H_  16
#define HD_ 64
#define M_  64
#define TD_ 3072
#define EPS_ 1e-6f

// ---------------------------------------------------------------------------
// SGEMM (NT): C[M][N] = A[M][K] * B[N][K]^T + bias[N]
// 128x128 tile, BK=16, 256 threads, 8x8 per-thread micro-tile, fp32 vector.
// ---------------------------------------------------------------------------
__global__ __launch_bounds__(256) void sgemm_nt_bias(
    const float* __restrict__ A, const float* __restrict__ Bm,
    const float* __restrict__ bias, float* __restrict__ C,
    int Mx, int Nx, int Kx)
{
    __shared__ float As[16][132];   // [k][m], +4 pad breaks pow2 strides
    __shared__ float Bs[16][132];   // [k][n]
    const int t  = threadIdx.x;
    const int bm = blockIdx.y * 128;
    const int bn = blockIdx.x * 128;
    const int tx = t & 15;          // n-dir
    const int ty = t >> 4;          // m-dir
    const int lr = t >> 2;          // 0..63 load row
    const int lk = (t & 3) * 4;     // 0,4,8,12 load k

    float acc[8][8];
#pragma unroll
    for (int i = 0; i < 8; i++)
#pragma unroll
        for (int j = 0; j < 8; j++) acc[i][j] = 0.f;

    const float* Ap0 = A  + (size_t)(bm + lr)      * Kx + lk;
    const float* Ap1 = A  + (size_t)(bm + lr + 64) * Kx + lk;
    const float* Bp0 = Bm + (size_t)(bn + lr)      * Kx + lk;
    const float* Bp1 = Bm + (size_t)(bn + lr + 64) * Kx + lk;

    for (int k0 = 0; k0 < Kx; k0 += 16) {
        float4 a0 = *(const float4*)(Ap0 + k0);
        float4 a1 = *(const float4*)(Ap1 + k0);
        float4 b0 = *(const float4*)(Bp0 + k0);
        float4 b1 = *(const float4*)(Bp1 + k0);
        __syncthreads();   // protect previous iteration's LDS reads
        As[lk+0][lr] = a0.x; As[lk+1][lr] = a0.y; As[lk+2][lr] = a0.z; As[lk+3][lr] = a0.w;
        As[lk+0][lr+64] = a1.x; As[lk+1][lr+64] = a1.y; As[lk+2][lr+64] = a1.z; As[lk+3][lr+64] = a1.w;
        Bs[lk+0][lr] = b0.x; Bs[lk+1][lr] = b0.y; Bs[lk+2][lr] = b0.z; Bs[lk+3][lr] = b0.w;
        Bs[lk+0][lr+64] = b1.x; Bs[lk+1][lr+64] = b1.y; Bs[lk+2][lr+64] = b1.z; Bs[lk+3][lr+64] = b1.w;
        __syncthreads();
#pragma unroll
        for (int kk = 0; kk < 16; kk++) {
            float av[8], bv[8];
            *(float4*)(av)   = *(const float4*)&As[kk][ty*8];
            *(float4*)(av+4) = *(const float4*)&As[kk][ty*8+4];
            *(float4*)(bv)   = *(const float4*)&Bs[kk][tx*8];
            *(float4*)(bv+4) = *(const float4*)&Bs[kk][tx*8+4];
#pragma unroll
            for (int i = 0; i < 8; i++)
#pragma unroll
                for (int j = 0; j < 8; j++)
                    acc[i][j] = fmaf(av[i], bv[j], acc[i][j]);
        }
    }

#pragma unroll
    for (int i = 0; i < 8; i++) {
        int row = bm + ty*8 + i;
        float* crow = C + (size_t)row * Nx + bn + tx*8;
        const float* brow = bias + bn + tx*8;
        float4 o0, o1;
        o0.x = acc[i][0] + brow[0]; o0.y = acc[i][1] + brow[1];
        o0.z = acc[i][2] + brow[2]; o0.w = acc[i][3] + brow[3];
        o1.x = acc[i][4] + brow[4]; o1.y = acc[i][5] + brow[5];
        o1.z = acc[i][6] + brow[6]; o1.w = acc[i][7] + brow[7];
        *(float4*)(crow)   = o0;
        *(float4*)(crow+4) = o1;
    }
}

// ---------------------------------------------------------------------------
// FAVOR+ feature map for ONE batch:
//   feat[h,n,m] = exp(dn.proj[m] - 0.5|dn|^2 - rowmax)/8 + eps
// grid (1024, 2): x = h*64 + n-chunk, y: 0=q part, 1=k part.
// 256 thr = 4 waves, each wave does 4 rows at once.
// ---------------------------------------------------------------------------
__global__ __launch_bounds__(256) void favor_features_kernel(
    const float* __restrict__ qkvb, const float* __restrict__ proj,
    float* __restrict__ qp, float* __restrict__ kp)
{
    __shared__ float  projT[64*64];   // projT[d*64+m]
    __shared__ float4 dnbuf[4][64];   // per wave: [d] -> 4 rows' dn[d]
    const int t = threadIdx.x;
    const int wave = t >> 6, lane = t & 63;
    const int part = blockIdx.y;
    float* outp = (part == 0) ? qp : kp;

    for (int i = t; i < 4096; i += 256)
        projT[(i & 63) * 64 + (i >> 6)] = proj[i];
    __syncthreads();

    const int h = blockIdx.x >> 6;             // 64 blocks per head
    const int n0 = (blockIdx.x & 63) * 64;
    const float* src = qkvb + part * D_ + h * HD_ + lane;

    for (int iter = 0; iter < 4; iter++) {
        const int n = n0 + iter * 16 + wave * 4;
        float v0 = src[(size_t)(n+0) * TD_];
        float v1 = src[(size_t)(n+1) * TD_];
        float v2 = src[(size_t)(n+2) * TD_];
        float v3 = src[(size_t)(n+3) * TD_];
        float4 dn = make_float4(v0*0.125f, v1*0.125f, v2*0.125f, v3*0.125f);
        dnbuf[wave][lane] = dn;
        float s0 = dn.x*dn.x, s1 = dn.y*dn.y, s2 = dn.z*dn.z, s3 = dn.w*dn.w;
#pragma unroll
        for (int off = 32; off >= 1; off >>= 1) {
            s0 += __shfl_xor(s0, off, 64);
            s1 += __shfl_xor(s1, off, 64);
            s2 += __shfl_xor(s2, off, 64);
            s3 += __shfl_xor(s3, off, 64);
        }
        float c0 = -0.5f*s0, c1 = -0.5f*s1, c2 = -0.5f*s2, c3 = -0.5f*s3;
#pragma unroll
        for (int d = 0; d < 64; d++) {
            float p = projT[d*64 + lane];     // conflict-free (lanes consecutive)
            float4 q = dnbuf[wave][d];        // b128 broadcast
            c0 = fmaf(q.x, p, c0);
            c1 = fmaf(q.y, p, c1);
            c2 = fmaf(q.z, p, c2);
            c3 = fmaf(q.w, p, c3);
        }
        float m0 = c0, m1 = c1, m2 = c2, m3 = c3;
#pragma unroll
        for (int off = 32; off >= 1; off >>= 1) {
            m0 = fmaxf(m0, __shfl_xor(m0, off, 64));
            m1 = fmaxf(m1, __shfl_xor(m1, off, 64));
            m2 = fmaxf(m2, __shfl_xor(m2, off, 64));
            m3 = fmaxf(m3, __shfl_xor(m3, off, 64));
        }
        float r0 = expf(c0 - m0) * 0.125f + EPS_;
        float r1 = expf(c1 - m1) * 0.125f + EPS_;
        float r2 = expf(c2 - m2) * 0.125f + EPS_;
        float r3 = expf(c3 - m3) * 0.125f + EPS_;
        size_t orow = ((size_t)h * N_ + n) * 64 + lane;
        outp[orow]       = r0;
        outp[orow + 64]  = r1;
        outp[orow + 128] = r2;
        outp[orow + 192] = r3;
    }
}

// ---------------------------------------------------------------------------
// ONE batch: kv[h,m,v] = sum_n kp[h,n,m]*v[h,n,v]; ksum[h,m] = sum_n kp[h,n,m]
// grid (16, 16): h x 256-n chunk. lane = m, wave = v-group of 16.
// Register partials then atomicAdd (kv zeroed first).
// ---------------------------------------------------------------------------
__global__ __launch_bounds__(256) void kv_kernel(
    const float* __restrict__ qkvb, const float* __restrict__ kp,
    float* __restrict__ kv, float* __restrict__ ksum)
{
    const int t = threadIdx.x, lane = t & 63, wave = t >> 6;
    const int h = blockIdx.x;
    const int n0 = blockIdx.y * 256;
    const float* vsrc  = qkvb + 2 * D_ + h * HD_ + wave * 16;
    const float* kpsrc = kp + (size_t)h * N_ * 64 + lane;

    float acc[16];
#pragma unroll
    for (int j = 0; j < 16; j++) acc[j] = 0.f;
    float ks = 0.f;

#pragma unroll 2
    for (int n = n0; n < n0 + 256; n++) {
        float kpv = kpsrc[(size_t)n * 64];               // coalesced
        const float4* vp = (const float4*)(vsrc + (size_t)n * TD_);
        float4 va = vp[0], vb = vp[1], vc = vp[2], vd = vp[3];  // wave-uniform broadcast
        ks += kpv;
        acc[0]  = fmaf(kpv, va.x, acc[0]);  acc[1]  = fmaf(kpv, va.y, acc[1]);
        acc[2]  = fmaf(kpv, va.z, acc[2]);  acc[3]  = fmaf(kpv, va.w, acc[3]);
        acc[4]  = fmaf(kpv, vb.x, acc[4]);  acc[5]  = fmaf(kpv, vb.y, acc[5]);
        acc[6]  = fmaf(kpv, vb.z, acc[6]);  acc[7]  = fmaf(kpv, vb.w, acc[7]);
        acc[8]  = fmaf(kpv, vc.x, acc[8]);  acc[9]  = fmaf(kpv, vc.y, acc[9]);
        acc[10] = fmaf(kpv, vc.z, acc[10]); acc[11] = fmaf(kpv, vc.w, acc[11]);
        acc[12] = fmaf(kpv, vd.x, acc[12]); acc[13] = fmaf(kpv, vd.y, acc[13]);
        acc[14] = fmaf(kpv, vd.z, acc[14]); acc[15] = fmaf(kpv, vd.w, acc[15]);
    }

    float* kvout = kv + (size_t)h * 4096 + lane * 64 + wave * 16;
#pragma unroll
    for (int j = 0; j < 16; j++) atomicAdd(&kvout[j], acc[j]);
    if (wave == 0) atomicAdd(&ksum[h * 64 + lane], ks);
}

// ---------------------------------------------------------------------------
// ONE batch:
// out[h,n,v] = (sum_m qp[h,n,m]*kv[h,m,v]) / (sum_m qp[h,n,m]*ksum[h,m] + eps)
// written to attn[n, h*64+v]. grid (16, 64). kv tile staged in LDS.
// ---------------------------------------------------------------------------
__global__ __launch_bounds__(256) void out_kernel(
    const float* __restrict__ qp, const float* __restrict__ kv,
    const float* __restrict__ ksum, float* __restrict__ attn)
{
    __shared__ float  kvs[4096];      // [m][v]
    __shared__ float  kss[64];
    __shared__ float4 qbuf[4][64];
    const int t = threadIdx.x, lane = t & 63, wave = t >> 6;
    const int h = blockIdx.x;
    const int n0 = blockIdx.y * 64;

    for (int i = t; i < 4096; i += 256) kvs[i] = kv[(size_t)h * 4096 + i];
    if (t < 64) kss[t] = ksum[h * 64 + t];
    __syncthreads();

    const float* qsrc = qp + (size_t)h * N_ * 64 + lane;
    float* adst = attn + h * HD_ + lane;

    for (int iter = 0; iter < 4; iter++) {
        const int n = n0 + iter * 16 + wave * 4;
        float q0 = qsrc[(size_t)(n+0) * 64];
        float q1 = qsrc[(size_t)(n+1) * 64];
        float q2 = qsrc[(size_t)(n+2) * 64];
        float q3 = qsrc[(size_t)(n+3) * 64];
        qbuf[wave][lane] = make_float4(q0, q1, q2, q3);
        float t0 = q0 * kss[lane], t1 = q1 * kss[lane];
        float t2 = q2 * kss[lane], t3 = q3 * kss[lane];
#pragma unroll
        for (int off = 32; off >= 1; off >>= 1) {
            t0 += __shfl_xor(t0, off, 64);
            t1 += __shfl_xor(t1, off, 64);
            t2 += __shfl_xor(t2, off, 64);
            t3 += __shfl_xor(t3, off, 64);
        }
        float a0 = 0.f, a1 = 0.f, a2 = 0.f, a3 = 0.f;
#pragma unroll
        for (int m = 0; m < 64; m++) {
            float kvv = kvs[m*64 + lane];     // conflict-free
            float4 q = qbuf[wave][m];         // b128 broadcast
            a0 = fmaf(q.x, kvv, a0);
            a1 = fmaf(q.y, kvv, a1);
            a2 = fmaf(q.z, kvv, a2);
            a3 = fmaf(q.w, kvv, a3);
        }
        adst[(size_t)(n+0) * D_] = a0 / (t0 + EPS_);
        adst[(size_t)(n+1) * D_] = a1 / (t1 + EPS_);
        adst[(size_t)(n+2) * D_] = a2 / (t2 + EPS_);
        adst[(size_t)(n+3) * D_] = a3 / (t3 + EPS_);
    }
}

// ---------------------------------------------------------------------------
// Per-batch chunked pipeline: workspace footprint ~81 MB (was 337 MB in R0,
// which we believe overran ws_size and page-faulted).
// ---------------------------------------------------------------------------
extern "C" void kernel_launch(void* const* d_in, const int* in_sizes, int n_in,
                              void* d_out, int out_size, void* d_ws, size_t ws_size,
                              hipStream_t stream)
{
    const float* x      = (const float*)d_in[0];   // [4,4096,1024]
    const float* qkv_w  = (const float*)d_in[1];   // [3072,1024]
    const float* qkv_b  = (const float*)d_in[2];   // [3072]
    const float* proj_w = (const float*)d_in[3];   // [1024,1024]
    const float* proj_b = (const float*)d_in[4];   // [1024]
    const float* pm     = (const float*)d_in[5];   // [64,64]
    float* out = (float*)d_out;                    // [4,4096,1024] fp32
    float* ws  = (float*)d_ws;

    // workspace layout (floats), single-batch buffers:
    float* qkvb = ws;                          // 4096*3072 = 12,582,912
    float* qp   = ws + 12582912;               // 16*4096*64 = 4,194,304
    float* kp   = qp + 4194304;                // 4,194,304
    float* kvb  = kp + 4194304;                // 16*64*64 = 65,536
    float* ksum = kvb + 65536;                 // 1,024
    float* attn = qkvb;                        // reuse (qkv dead after kv_kernel)
    // total: 21,038,080 floats = 80.3 MB

    for (int b = 0; b < B_; b++) {
        const float* xb = x + (size_t)b * N_ * D_;
        float* outb = out + (size_t)b * N_ * D_;

        hipMemsetAsync(kvb, 0, (65536 + 1024) * sizeof(float), stream);

        // 1) qkvb = xb @ qkv_w^T + qkv_b    [4096 x 3072]
        dim3 g1(TD_ / 128, N_ / 128);          // (24, 32)
        sgemm_nt_bias<<<g1, 256, 0, stream>>>(xb, qkv_w, qkv_b, qkvb, N_, TD_, D_);

        // 2) FAVOR features for q and k
        dim3 g2(1024, 2);
        favor_features_kernel<<<g2, 256, 0, stream>>>(qkvb, pm, qp, kp);

        // 3) kv einsum + k_sum
        dim3 g3(16, 16);
        kv_kernel<<<g3, 256, 0, stream>>>(qkvb, kp, kvb, ksum);

        // 4) out einsum + normalizer -> attn [4096 x 1024]
        dim3 g4(16, 64);
        out_kernel<<<g4, 256, 0, stream>>>(qp, kvb, ksum, attn);

        // 5) outb = attn @ proj_w^T + proj_b
        dim3 g5(D_ / 128, N_ / 128);           // (8, 32)
        sgemm_nt_bias<<<g5, 256, 0, stream>>>(attn, proj_w, proj_b, outb, N_, D_, D_);
    }
}

// Round 3
// 1365.360 us; speedup vs baseline: 1.7868x; 1.7868x over previous
//
#include <hip/hip_runtime.h>
#include <math.h>

#define B_  4
#define N_  4096
#define D_  1024
#define H_  16
#define HD_ 64
#define M_  64
#define TD_ 3072
#define EPS_ 1e-6f

typedef __attribute__((ext_vector_type(8))) short short8;
typedef __attribute__((ext_vector_type(4))) float floatx4;
typedef unsigned int uint32;

// Split two fp32 into packed hi-bf16 pair and lo-bf16 pair.
// hi = truncate-to-bf16 (bit surgery, no rounding), lo = bf16(f - hi).
// Dropped lo*lo term in the 3-MFMA product is <= 2^-16 relative.
__device__ __forceinline__ void cvt2(float f0, float f1, uint32& hp, uint32& lp)
{
    uint32 b0 = __float_as_uint(f0), b1 = __float_as_uint(f1);
    hp = (b1 & 0xFFFF0000u) | (b0 >> 16);
    float l0 = f0 - __uint_as_float(b0 & 0xFFFF0000u);
    float l1 = f1 - __uint_as_float(b1 & 0xFFFF0000u);
    lp = (__float_as_uint(l1) & 0xFFFF0000u) | (__float_as_uint(l0) >> 16);
}

// ---------------------------------------------------------------------------
// Split-bf16 MFMA GEMM (NT): C[M][N] = A[M][K] * B[N][K]^T + bias[N]
// fp32 in/out, internally hi/lo bf16 with 3 MFMAs per fragment pair.
// 128x128 tile, BK=32, 256 thr = 2x2 waves, 64x64 per wave (4x4 16x16 frags).
// LDS rows padded to 40 ushorts (80 B) -> uniform bank distribution.
// ---------------------------------------------------------------------------
#define LDSTR 40

__global__ __launch_bounds__(256, 2) void gemm_bf16x2_nt_bias(
    const float* __restrict__ A, const float* __restrict__ Bm,
    const float* __restrict__ bias, float* __restrict__ C,
    int Nx, int Kx)
{
    __shared__ __align__(16) unsigned short AhiS[128*LDSTR], AloS[128*LDSTR];
    __shared__ __align__(16) unsigned short BhiS[128*LDSTR], BloS[128*LDSTR];

    const int t    = threadIdx.x;
    const int bm   = blockIdx.y * 128, bn = blockIdx.x * 128;
    const int lane = t & 63, wave = t >> 6;
    const int wm   = wave >> 1, wn = wave & 1;
    const int l16  = lane & 15, quad = lane >> 4;
    const int r    = t >> 1;          // staging row 0..127
    const int ko   = (t & 1) * 16;    // staging k-offset 0/16

    floatx4 acc[4][4];
#pragma unroll
    for (int i = 0; i < 4; i++)
#pragma unroll
        for (int j = 0; j < 4; j++) acc[i][j] = (floatx4)0.f;

    const float* ap = A  + (size_t)(bm + r) * Kx + ko;
    const float* bp = Bm + (size_t)(bn + r) * Kx + ko;

    for (int k0 = 0; k0 < Kx; k0 += 32) {
        float4 fa0 = *(const float4*)(ap + k0);
        float4 fa1 = *(const float4*)(ap + k0 + 4);
        float4 fa2 = *(const float4*)(ap + k0 + 8);
        float4 fa3 = *(const float4*)(ap + k0 + 12);
        float4 fb0 = *(const float4*)(bp + k0);
        float4 fb1 = *(const float4*)(bp + k0 + 4);
        float4 fb2 = *(const float4*)(bp + k0 + 8);
        float4 fb3 = *(const float4*)(bp + k0 + 12);

        __syncthreads();   // prior iteration's fragment reads complete

        uint4 h0, h1, l0, l1;
        cvt2(fa0.x, fa0.y, h0.x, l0.x); cvt2(fa0.z, fa0.w, h0.y, l0.y);
        cvt2(fa1.x, fa1.y, h0.z, l0.z); cvt2(fa1.z, fa1.w, h0.w, l0.w);
        cvt2(fa2.x, fa2.y, h1.x, l1.x); cvt2(fa2.z, fa2.w, h1.y, l1.y);
        cvt2(fa3.x, fa3.y, h1.z, l1.z); cvt2(fa3.z, fa3.w, h1.w, l1.w);
        *(uint4*)&AhiS[r*LDSTR + ko]     = h0;
        *(uint4*)&AhiS[r*LDSTR + ko + 8] = h1;
        *(uint4*)&AloS[r*LDSTR + ko]     = l0;
        *(uint4*)&AloS[r*LDSTR + ko + 8] = l1;

        cvt2(fb0.x, fb0.y, h0.x, l0.x); cvt2(fb0.z, fb0.w, h0.y, l0.y);
        cvt2(fb1.x, fb1.y, h0.z, l0.z); cvt2(fb1.z, fb1.w, h0.w, l0.w);
        cvt2(fb2.x, fb2.y, h1.x, l1.x); cvt2(fb2.z, fb2.w, h1.y, l1.y);
        cvt2(fb3.x, fb3.y, h1.z, l1.z); cvt2(fb3.z, fb3.w, h1.w, l1.w);
        *(uint4*)&BhiS[r*LDSTR + ko]     = h0;
        *(uint4*)&BhiS[r*LDSTR + ko + 8] = h1;
        *(uint4*)&BloS[r*LDSTR + ko]     = l0;
        *(uint4*)&BloS[r*LDSTR + ko + 8] = l1;

        __syncthreads();

        short8 ah[4], al[4], bh[4], bl[4];
#pragma unroll
        for (int mi = 0; mi < 4; mi++) {
            int row = (wm*64 + mi*16 + l16) * LDSTR + quad*8;
            ah[mi] = *(const short8*)&AhiS[row];
            al[mi] = *(const short8*)&AloS[row];
        }
#pragma unroll
        for (int ni = 0; ni < 4; ni++) {
            int row = (wn*64 + ni*16 + l16) * LDSTR + quad*8;
            bh[ni] = *(const short8*)&BhiS[row];
            bl[ni] = *(const short8*)&BloS[row];
        }
#pragma unroll
        for (int mi = 0; mi < 4; mi++)
#pragma unroll
            for (int ni = 0; ni < 4; ni++) {
                floatx4 d = acc[mi][ni];
                d = __builtin_amdgcn_mfma_f32_16x16x32_bf16(ah[mi], bh[ni], d, 0, 0, 0);
                d = __builtin_amdgcn_mfma_f32_16x16x32_bf16(al[mi], bh[ni], d, 0, 0, 0);
                d = __builtin_amdgcn_mfma_f32_16x16x32_bf16(ah[mi], bl[ni], d, 0, 0, 0);
                acc[mi][ni] = d;
            }
    }

    // epilogue: C[row][col] = acc + bias[col]
    float bia[4];
#pragma unroll
    for (int ni = 0; ni < 4; ni++)
        bia[ni] = bias[bn + wn*64 + ni*16 + l16];
#pragma unroll
    for (int mi = 0; mi < 4; mi++)
#pragma unroll
        for (int rr = 0; rr < 4; rr++) {
            int row = bm + wm*64 + mi*16 + quad*4 + rr;
            float* crow = C + (size_t)row * Nx + bn + wn*64 + l16;
#pragma unroll
            for (int ni = 0; ni < 4; ni++)
                crow[ni*16] = acc[mi][ni][rr] + bia[ni];
        }
}

// ---------------------------------------------------------------------------
// FAVOR+ feature map for ONE batch:
//   feat[h,n,m] = exp(dn.proj[m] - 0.5|dn|^2 - rowmax)/8 + eps
// ---------------------------------------------------------------------------
__global__ __launch_bounds__(256) void favor_features_kernel(
    const float* __restrict__ qkvb, const float* __restrict__ proj,
    float* __restrict__ qp, float* __restrict__ kp)
{
    __shared__ float  projT[64*64];   // projT[d*64+m]
    __shared__ float4 dnbuf[4][64];   // per wave: [d] -> 4 rows' dn[d]
    const int t = threadIdx.x;
    const int wave = t >> 6, lane = t & 63;
    const int part = blockIdx.y;
    float* outp = (part == 0) ? qp : kp;

    for (int i = t; i < 4096; i += 256)
        projT[(i & 63) * 64 + (i >> 6)] = proj[i];
    __syncthreads();

    const int h = blockIdx.x >> 6;             // 64 blocks per head
    const int n0 = (blockIdx.x & 63) * 64;
    const float* src = qkvb + part * D_ + h * HD_ + lane;

    for (int iter = 0; iter < 4; iter++) {
        const int n = n0 + iter * 16 + wave * 4;
        float v0 = src[(size_t)(n+0) * TD_];
        float v1 = src[(size_t)(n+1) * TD_];
        float v2 = src[(size_t)(n+2) * TD_];
        float v3 = src[(size_t)(n+3) * TD_];
        float4 dn = make_float4(v0*0.125f, v1*0.125f, v2*0.125f, v3*0.125f);
        dnbuf[wave][lane] = dn;
        float s0 = dn.x*dn.x, s1 = dn.y*dn.y, s2 = dn.z*dn.z, s3 = dn.w*dn.w;
#pragma unroll
        for (int off = 32; off >= 1; off >>= 1) {
            s0 += __shfl_xor(s0, off, 64);
            s1 += __shfl_xor(s1, off, 64);
            s2 += __shfl_xor(s2, off, 64);
            s3 += __shfl_xor(s3, off, 64);
        }
        float c0 = -0.5f*s0, c1 = -0.5f*s1, c2 = -0.5f*s2, c3 = -0.5f*s3;
#pragma unroll
        for (int d = 0; d < 64; d++) {
            float p = projT[d*64 + lane];     // conflict-free (lanes consecutive)
            float4 q = dnbuf[wave][d];        // b128 broadcast
            c0 = fmaf(q.x, p, c0);
            c1 = fmaf(q.y, p, c1);
            c2 = fmaf(q.z, p, c2);
            c3 = fmaf(q.w, p, c3);
        }
        float m0 = c0, m1 = c1, m2 = c2, m3 = c3;
#pragma unroll
        for (int off = 32; off >= 1; off >>= 1) {
            m0 = fmaxf(m0, __shfl_xor(m0, off, 64));
            m1 = fmaxf(m1, __shfl_xor(m1, off, 64));
            m2 = fmaxf(m2, __shfl_xor(m2, off, 64));
            m3 = fmaxf(m3, __shfl_xor(m3, off, 64));
        }
        float r0 = expf(c0 - m0) * 0.125f + EPS_;
        float r1 = expf(c1 - m1) * 0.125f + EPS_;
        float r2 = expf(c2 - m2) * 0.125f + EPS_;
        float r3 = expf(c3 - m3) * 0.125f + EPS_;
        size_t orow = ((size_t)h * N_ + n) * 64 + lane;
        outp[orow]       = r0;
        outp[orow + 64]  = r1;
        outp[orow + 128] = r2;
        outp[orow + 192] = r3;
    }
}

// ---------------------------------------------------------------------------
// ONE batch: kv[h,m,v] = sum_n kp[h,n,m]*v[h,n,v]; ksum[h,m] = sum_n kp[h,n,m]
// ---------------------------------------------------------------------------
__global__ __launch_bounds__(256) void kv_kernel(
    const float* __restrict__ qkvb, const float* __restrict__ kp,
    float* __restrict__ kv, float* __restrict__ ksum)
{
    const int t = threadIdx.x, lane = t & 63, wave = t >> 6;
    const int h = blockIdx.x;
    const int n0 = blockIdx.y * 256;
    const float* vsrc  = qkvb + 2 * D_ + h * HD_ + wave * 16;
    const float* kpsrc = kp + (size_t)h * N_ * 64 + lane;

    float acc[16];
#pragma unroll
    for (int j = 0; j < 16; j++) acc[j] = 0.f;
    float ks = 0.f;

#pragma unroll 2
    for (int n = n0; n < n0 + 256; n++) {
        float kpv = kpsrc[(size_t)n * 64];               // coalesced
        const float4* vp = (const float4*)(vsrc + (size_t)n * TD_);
        float4 va = vp[0], vb = vp[1], vc = vp[2], vd = vp[3];  // wave-uniform broadcast
        ks += kpv;
        acc[0]  = fmaf(kpv, va.x, acc[0]);  acc[1]  = fmaf(kpv, va.y, acc[1]);
        acc[2]  = fmaf(kpv, va.z, acc[2]);  acc[3]  = fmaf(kpv, va.w, acc[3]);
        acc[4]  = fmaf(kpv, vb.x, acc[4]);  acc[5]  = fmaf(kpv, vb.y, acc[5]);
        acc[6]  = fmaf(kpv, vb.z, acc[6]);  acc[7]  = fmaf(kpv, vb.w, acc[7]);
        acc[8]  = fmaf(kpv, vc.x, acc[8]);  acc[9]  = fmaf(kpv, vc.y, acc[9]);
        acc[10] = fmaf(kpv, vc.z, acc[10]); acc[11] = fmaf(kpv, vc.w, acc[11]);
        acc[12] = fmaf(kpv, vd.x, acc[12]); acc[13] = fmaf(kpv, vd.y, acc[13]);
        acc[14] = fmaf(kpv, vd.z, acc[14]); acc[15] = fmaf(kpv, vd.w, acc[15]);
    }

    float* kvout = kv + (size_t)h * 4096 + lane * 64 + wave * 16;
#pragma unroll
    for (int j = 0; j < 16; j++) atomicAdd(&kvout[j], acc[j]);
    if (wave == 0) atomicAdd(&ksum[h * 64 + lane], ks);
}

// ---------------------------------------------------------------------------
// ONE batch:
// out[h,n,v] = (sum_m qp[h,n,m]*kv[h,m,v]) / (sum_m qp[h,n,m]*ksum[h,m] + eps)
// ---------------------------------------------------------------------------
__global__ __launch_bounds__(256) void out_kernel(
    const float* __restrict__ qp, const float* __restrict__ kv,
    const float* __restrict__ ksum, float* __restrict__ attn)
{
    __shared__ float  kvs[4096];      // [m][v]
    __shared__ float  kss[64];
    __shared__ float4 qbuf[4][64];
    const int t = threadIdx.x, lane = t & 63, wave = t >> 6;
    const int h = blockIdx.x;
    const int n0 = blockIdx.y * 64;

    for (int i = t; i < 4096; i += 256) kvs[i] = kv[(size_t)h * 4096 + i];
    if (t < 64) kss[t] = ksum[h * 64 + t];
    __syncthreads();

    const float* qsrc = qp + (size_t)h * N_ * 64 + lane;
    float* adst = attn + h * HD_ + lane;

    for (int iter = 0; iter < 4; iter++) {
        const int n = n0 + iter * 16 + wave * 4;
        float q0 = qsrc[(size_t)(n+0) * 64];
        float q1 = qsrc[(size_t)(n+1) * 64];
        float q2 = qsrc[(size_t)(n+2) * 64];
        float q3 = qsrc[(size_t)(n+3) * 64];
        qbuf[wave][lane] = make_float4(q0, q1, q2, q3);
        float t0 = q0 * kss[lane], t1 = q1 * kss[lane];
        float t2 = q2 * kss[lane], t3 = q3 * kss[lane];
#pragma unroll
        for (int off = 32; off >= 1; off >>= 1) {
            t0 += __shfl_xor(t0, off, 64);
            t1 += __shfl_xor(t1, off, 64);
            t2 += __shfl_xor(t2, off, 64);
            t3 += __shfl_xor(t3, off, 64);
        }
        float a0 = 0.f, a1 = 0.f, a2 = 0.f, a3 = 0.f;
#pragma unroll
        for (int m = 0; m < 64; m++) {
            float kvv = kvs[m*64 + lane];     // conflict-free
            float4 q = qbuf[wave][m];         // b128 broadcast
            a0 = fmaf(q.x, kvv, a0);
            a1 = fmaf(q.y, kvv, a1);
            a2 = fmaf(q.z, kvv, a2);
            a3 = fmaf(q.w, kvv, a3);
        }
        adst[(size_t)(n+0) * D_] = a0 / (t0 + EPS_);
        adst[(size_t)(n+1) * D_] = a1 / (t1 + EPS_);
        adst[(size_t)(n+2) * D_] = a2 / (t2 + EPS_);
        adst[(size_t)(n+3) * D_] = a3 / (t3 + EPS_);
    }
}

// ---------------------------------------------------------------------------
extern "C" void kernel_launch(void* const* d_in, const int* in_sizes, int n_in,
                              void* d_out, int out_size, void* d_ws, size_t ws_size,
                              hipStream_t stream)
{
    const float* x      = (const float*)d_in[0];   // [4,4096,1024]
    const float* qkv_w  = (const float*)d_in[1];   // [3072,1024]
    const float* qkv_b  = (const float*)d_in[2];   // [3072]
    const float* proj_w = (const float*)d_in[3];   // [1024,1024]
    const float* proj_b = (const float*)d_in[4];   // [1024]
    const float* pm     = (const float*)d_in[5];   // [64,64]
    float* out = (float*)d_out;                    // [4,4096,1024] fp32
    float* ws  = (float*)d_ws;

    // workspace layout (floats), single-batch buffers (~80 MB total):
    float* qkvb = ws;                          // 4096*3072 = 12,582,912
    float* qp   = ws + 12582912;               // 16*4096*64 = 4,194,304
    float* kp   = qp + 4194304;                // 4,194,304
    float* kvb  = kp + 4194304;                // 16*64*64 = 65,536
    float* ksum = kvb + 65536;                 // 1,024
    float* attn = qkvb;                        // reuse (qkv dead after kv_kernel)

    for (int b = 0; b < B_; b++) {
        const float* xb = x + (size_t)b * N_ * D_;
        float* outb = out + (size_t)b * N_ * D_;

        hipMemsetAsync(kvb, 0, (65536 + 1024) * sizeof(float), stream);

        // 1) qkvb = xb @ qkv_w^T + qkv_b    [4096 x 3072]
        dim3 g1(TD_ / 128, N_ / 128);          // (24, 32)
        gemm_bf16x2_nt_bias<<<g1, 256, 0, stream>>>(xb, qkv_w, qkv_b, qkvb, TD_, D_);

        // 2) FAVOR features for q and k
        dim3 g2(1024, 2);
        favor_features_kernel<<<g2, 256, 0, stream>>>(qkvb, pm, qp, kp);

        // 3) kv einsum + k_sum
        dim3 g3(16, 16);
        kv_kernel<<<g3, 256, 0, stream>>>(qkvb, kp, kvb, ksum);

        // 4) out einsum + normalizer -> attn [4096 x 1024]
        dim3 g4(16, 64);
        out_kernel<<<g4, 256, 0, stream>>>(qp, kvb, ksum, attn);

        // 5) outb = attn @ proj_w^T + proj_b
        dim3 g5(D_ / 128, N_ / 128);           // (8, 32)
        gemm_bf16x2_nt_bias<<<g5, 256, 0, stream>>>(attn, proj_w, proj_b, outb, D_, D_);
    }
}

// Round 4
// 1106.766 us; speedup vs baseline: 2.2043x; 1.2336x over previous
//
#include <hip/hip_runtime.h>
#include <math.h>

#define B_  4
#define N_  4096
#define D_  1024
#define H_  16
#define HD_ 64
#define M_  64
#define TD_ 3072
#define EPS_ 1e-6f

typedef __attribute__((ext_vector_type(8))) short short8;
typedef __attribute__((ext_vector_type(4))) float floatx4;
typedef unsigned int uint32;

// Split two fp32 into packed hi-bf16 pair and lo-bf16 pair.
// hi = truncate-to-bf16 (bit surgery), lo = bf16(f - hi).
__device__ __forceinline__ void cvt2(float f0, float f1, uint32& hp, uint32& lp)
{
    uint32 b0 = __float_as_uint(f0), b1 = __float_as_uint(f1);
    hp = (b1 & 0xFFFF0000u) | (b0 >> 16);
    float l0 = f0 - __uint_as_float(b0 & 0xFFFF0000u);
    float l1 = f1 - __uint_as_float(b1 & 0xFFFF0000u);
    lp = (__float_as_uint(l1) & 0xFFFF0000u) | (__float_as_uint(l0) >> 16);
}

// ---------------------------------------------------------------------------
// Split-bf16 MFMA GEMM (NT): C[M][N] = A[M][K] * B[N][K]^T + bias[N]
// ---------------------------------------------------------------------------
#define LDSTR 40

__global__ __launch_bounds__(256, 2) void gemm_bf16x2_nt_bias(
    const float* __restrict__ A, const float* __restrict__ Bm,
    const float* __restrict__ bias, float* __restrict__ C,
    int Nx, int Kx)
{
    __shared__ __align__(16) unsigned short AhiS[128*LDSTR], AloS[128*LDSTR];
    __shared__ __align__(16) unsigned short BhiS[128*LDSTR], BloS[128*LDSTR];

    const int t    = threadIdx.x;
    const int bm   = blockIdx.y * 128, bn = blockIdx.x * 128;
    const int lane = t & 63, wave = t >> 6;
    const int wm   = wave >> 1, wn = wave & 1;
    const int l16  = lane & 15, quad = lane >> 4;
    const int r    = t >> 1;          // staging row 0..127
    const int ko   = (t & 1) * 16;    // staging k-offset 0/16

    floatx4 acc[4][4];
#pragma unroll
    for (int i = 0; i < 4; i++)
#pragma unroll
        for (int j = 0; j < 4; j++) acc[i][j] = (floatx4)0.f;

    const float* ap = A  + (size_t)(bm + r) * Kx + ko;
    const float* bp = Bm + (size_t)(bn + r) * Kx + ko;

    for (int k0 = 0; k0 < Kx; k0 += 32) {
        float4 fa0 = *(const float4*)(ap + k0);
        float4 fa1 = *(const float4*)(ap + k0 + 4);
        float4 fa2 = *(const float4*)(ap + k0 + 8);
        float4 fa3 = *(const float4*)(ap + k0 + 12);
        float4 fb0 = *(const float4*)(bp + k0);
        float4 fb1 = *(const float4*)(bp + k0 + 4);
        float4 fb2 = *(const float4*)(bp + k0 + 8);
        float4 fb3 = *(const float4*)(bp + k0 + 12);

        __syncthreads();   // prior iteration's fragment reads complete

        uint4 h0, h1, l0, l1;
        cvt2(fa0.x, fa0.y, h0.x, l0.x); cvt2(fa0.z, fa0.w, h0.y, l0.y);
        cvt2(fa1.x, fa1.y, h0.z, l0.z); cvt2(fa1.z, fa1.w, h0.w, l0.w);
        cvt2(fa2.x, fa2.y, h1.x, l1.x); cvt2(fa2.z, fa2.w, h1.y, l1.y);
        cvt2(fa3.x, fa3.y, h1.z, l1.z); cvt2(fa3.z, fa3.w, h1.w, l1.w);
        *(uint4*)&AhiS[r*LDSTR + ko]     = h0;
        *(uint4*)&AhiS[r*LDSTR + ko + 8] = h1;
        *(uint4*)&AloS[r*LDSTR + ko]     = l0;
        *(uint4*)&AloS[r*LDSTR + ko + 8] = l1;

        cvt2(fb0.x, fb0.y, h0.x, l0.x); cvt2(fb0.z, fb0.w, h0.y, l0.y);
        cvt2(fb1.x, fb1.y, h0.z, l0.z); cvt2(fb1.z, fb1.w, h0.w, l0.w);
        cvt2(fb2.x, fb2.y, h1.x, l1.x); cvt2(fb2.z, fb2.w, h1.y, l1.y);
        cvt2(fb3.x, fb3.y, h1.z, l1.z); cvt2(fb3.z, fb3.w, h1.w, l1.w);
        *(uint4*)&BhiS[r*LDSTR + ko]     = h0;
        *(uint4*)&BhiS[r*LDSTR + ko + 8] = h1;
        *(uint4*)&BloS[r*LDSTR + ko]     = l0;
        *(uint4*)&BloS[r*LDSTR + ko + 8] = l1;

        __syncthreads();

        short8 ah[4], al[4], bh[4], bl[4];
#pragma unroll
        for (int mi = 0; mi < 4; mi++) {
            int row = (wm*64 + mi*16 + l16) * LDSTR + quad*8;
            ah[mi] = *(const short8*)&AhiS[row];
            al[mi] = *(const short8*)&AloS[row];
        }
#pragma unroll
        for (int ni = 0; ni < 4; ni++) {
            int row = (wn*64 + ni*16 + l16) * LDSTR + quad*8;
            bh[ni] = *(const short8*)&BhiS[row];
            bl[ni] = *(const short8*)&BloS[row];
        }
#pragma unroll
        for (int mi = 0; mi < 4; mi++)
#pragma unroll
            for (int ni = 0; ni < 4; ni++) {
                floatx4 d = acc[mi][ni];
                d = __builtin_amdgcn_mfma_f32_16x16x32_bf16(ah[mi], bh[ni], d, 0, 0, 0);
                d = __builtin_amdgcn_mfma_f32_16x16x32_bf16(al[mi], bh[ni], d, 0, 0, 0);
                d = __builtin_amdgcn_mfma_f32_16x16x32_bf16(ah[mi], bl[ni], d, 0, 0, 0);
                acc[mi][ni] = d;
            }
    }

    // epilogue: C[row][col] = acc + bias[col]
    float bia[4];
#pragma unroll
    for (int ni = 0; ni < 4; ni++)
        bia[ni] = bias[bn + wn*64 + ni*16 + l16];
#pragma unroll
    for (int mi = 0; mi < 4; mi++)
#pragma unroll
        for (int rr = 0; rr < 4; rr++) {
            int row = bm + wm*64 + mi*16 + quad*4 + rr;
            float* crow = C + (size_t)row * Nx + bn + wn*64 + l16;
#pragma unroll
            for (int ni = 0; ni < 4; ni++)
                crow[ni*16] = acc[mi][ni][rr] + bia[ni];
        }
}

// ---------------------------------------------------------------------------
// FAVOR+ feature map for ONE batch:
//   feat[h,n,m] = exp(dn.proj[m] - 0.5|dn|^2 - rowmax)/8 + eps
// ---------------------------------------------------------------------------
__global__ __launch_bounds__(256) void favor_features_kernel(
    const float* __restrict__ qkvb, const float* __restrict__ proj,
    float* __restrict__ qp, float* __restrict__ kp)
{
    __shared__ float  projT[64*64];   // projT[d*64+m]
    __shared__ float4 dnbuf[4][64];   // per wave: [d] -> 4 rows' dn[d]
    const int t = threadIdx.x;
    const int wave = t >> 6, lane = t & 63;
    const int part = blockIdx.y;
    float* outp = (part == 0) ? qp : kp;

    for (int i = t; i < 4096; i += 256)
        projT[(i & 63) * 64 + (i >> 6)] = proj[i];
    __syncthreads();

    const int h = blockIdx.x >> 6;             // 64 blocks per head
    const int n0 = (blockIdx.x & 63) * 64;
    const float* src = qkvb + part * D_ + h * HD_ + lane;

    for (int iter = 0; iter < 4; iter++) {
        const int n = n0 + iter * 16 + wave * 4;
        float v0 = src[(size_t)(n+0) * TD_];
        float v1 = src[(size_t)(n+1) * TD_];
        float v2 = src[(size_t)(n+2) * TD_];
        float v3 = src[(size_t)(n+3) * TD_];
        float4 dn = make_float4(v0*0.125f, v1*0.125f, v2*0.125f, v3*0.125f);
        dnbuf[wave][lane] = dn;
        float s0 = dn.x*dn.x, s1 = dn.y*dn.y, s2 = dn.z*dn.z, s3 = dn.w*dn.w;
#pragma unroll
        for (int off = 32; off >= 1; off >>= 1) {
            s0 += __shfl_xor(s0, off, 64);
            s1 += __shfl_xor(s1, off, 64);
            s2 += __shfl_xor(s2, off, 64);
            s3 += __shfl_xor(s3, off, 64);
        }
        float c0 = -0.5f*s0, c1 = -0.5f*s1, c2 = -0.5f*s2, c3 = -0.5f*s3;
#pragma unroll
        for (int d = 0; d < 64; d++) {
            float p = projT[d*64 + lane];     // conflict-free (lanes consecutive)
            float4 q = dnbuf[wave][d];        // b128 broadcast
            c0 = fmaf(q.x, p, c0);
            c1 = fmaf(q.y, p, c1);
            c2 = fmaf(q.z, p, c2);
            c3 = fmaf(q.w, p, c3);
        }
        float m0 = c0, m1 = c1, m2 = c2, m3 = c3;
#pragma unroll
        for (int off = 32; off >= 1; off >>= 1) {
            m0 = fmaxf(m0, __shfl_xor(m0, off, 64));
            m1 = fmaxf(m1, __shfl_xor(m1, off, 64));
            m2 = fmaxf(m2, __shfl_xor(m2, off, 64));
            m3 = fmaxf(m3, __shfl_xor(m3, off, 64));
        }
        float r0 = expf(c0 - m0) * 0.125f + EPS_;
        float r1 = expf(c1 - m1) * 0.125f + EPS_;
        float r2 = expf(c2 - m2) * 0.125f + EPS_;
        float r3 = expf(c3 - m3) * 0.125f + EPS_;
        size_t orow = ((size_t)h * N_ + n) * 64 + lane;
        outp[orow]       = r0;
        outp[orow + 64]  = r1;
        outp[orow + 128] = r2;
        outp[orow + 192] = r3;
    }
}

// ---------------------------------------------------------------------------
// kv stage 1: per (h, n-chunk of 128) partial sums, no atomics.
// kvpart[h][c][m][v] = sum_{n in chunk} kp[h,n,m] * v[h,n,v]
// kspart[h][c][m]    = sum_{n in chunk} kp[h,n,m]
// thread t -> m0=(t&15)*4, v0=(t>>4)*4; 4x4 register tile; 128 n per block.
// ---------------------------------------------------------------------------
__global__ __launch_bounds__(256) void kv_partial_kernel(
    const float* __restrict__ qkvb, const float* __restrict__ kp,
    float* __restrict__ kvpart, float* __restrict__ kspart)
{
    const int t = threadIdx.x;
    const int h = blockIdx.x;
    const int c = blockIdx.y;
    const int n0 = c * 128;
    const int m0 = (t & 15) * 4;
    const int v0 = (t >> 4) * 4;

    const float* kpsrc = kp + ((size_t)h * N_ + n0) * 64 + m0;
    const float* vsrc  = qkvb + (size_t)n0 * TD_ + 2 * D_ + h * HD_ + v0;

    float acc[4][4];
#pragma unroll
    for (int i = 0; i < 4; i++)
#pragma unroll
        for (int j = 0; j < 4; j++) acc[i][j] = 0.f;
    float ks[4] = {0.f, 0.f, 0.f, 0.f};

#pragma unroll 4
    for (int n = 0; n < 128; n++) {
        float4 kq = *(const float4*)(kpsrc + (size_t)n * 64);
        float4 vq = *(const float4*)(vsrc  + (size_t)n * TD_);
        acc[0][0] = fmaf(kq.x, vq.x, acc[0][0]);
        acc[0][1] = fmaf(kq.x, vq.y, acc[0][1]);
        acc[0][2] = fmaf(kq.x, vq.z, acc[0][2]);
        acc[0][3] = fmaf(kq.x, vq.w, acc[0][3]);
        acc[1][0] = fmaf(kq.y, vq.x, acc[1][0]);
        acc[1][1] = fmaf(kq.y, vq.y, acc[1][1]);
        acc[1][2] = fmaf(kq.y, vq.z, acc[1][2]);
        acc[1][3] = fmaf(kq.y, vq.w, acc[1][3]);
        acc[2][0] = fmaf(kq.z, vq.x, acc[2][0]);
        acc[2][1] = fmaf(kq.z, vq.y, acc[2][1]);
        acc[2][2] = fmaf(kq.z, vq.z, acc[2][2]);
        acc[2][3] = fmaf(kq.z, vq.w, acc[2][3]);
        acc[3][0] = fmaf(kq.w, vq.x, acc[3][0]);
        acc[3][1] = fmaf(kq.w, vq.y, acc[3][1]);
        acc[3][2] = fmaf(kq.w, vq.z, acc[3][2]);
        acc[3][3] = fmaf(kq.w, vq.w, acc[3][3]);
        if (v0 == 0) {   // one v-group accumulates ksum (uniform per 16-thread group)
            ks[0] += kq.x; ks[1] += kq.y; ks[2] += kq.z; ks[3] += kq.w;
        }
    }

    float* kvp = kvpart + (((size_t)h * 32 + c) * 4096) + m0 * 64 + v0;
#pragma unroll
    for (int i = 0; i < 4; i++)
        *(float4*)(kvp + i * 64) = make_float4(acc[i][0], acc[i][1], acc[i][2], acc[i][3]);

    if (v0 == 0) {
        float* ksp = kspart + ((size_t)h * 32 + c) * 64 + m0;
        *(float4*)ksp = make_float4(ks[0], ks[1], ks[2], ks[3]);
    }
}

// ---------------------------------------------------------------------------
// kv stage 2: reduce 32 chunk-partials -> kv[h][4096], ksum[h][64]
// ---------------------------------------------------------------------------
__global__ __launch_bounds__(256) void kv_reduce_kernel(
    const float* __restrict__ kvpart, const float* __restrict__ kspart,
    float* __restrict__ kv, float* __restrict__ ksum)
{
    const int t = threadIdx.x;
    const int h = blockIdx.x;
    const int e0 = t * 16;

    float4 s[4];
#pragma unroll
    for (int i = 0; i < 4; i++) s[i] = make_float4(0.f, 0.f, 0.f, 0.f);
    float kss = 0.f;

    for (int c = 0; c < 32; c++) {
        const float* p = kvpart + (((size_t)h * 32 + c) * 4096) + e0;
#pragma unroll
        for (int i = 0; i < 4; i++) {
            float4 x = *(const float4*)(p + i * 4);
            s[i].x += x.x; s[i].y += x.y; s[i].z += x.z; s[i].w += x.w;
        }
        if (t < 64) kss += kspart[((size_t)h * 32 + c) * 64 + t];
    }

    float* kvo = kv + (size_t)h * 4096 + e0;
#pragma unroll
    for (int i = 0; i < 4; i++) *(float4*)(kvo + i * 4) = s[i];
    if (t < 64) ksum[h * 64 + t] = kss;
}

// ---------------------------------------------------------------------------
// out[h,n,v] = (sum_m qp[h,n,m]*kv[h,m,v]) / (sum_m qp[h,n,m]*ksum[h,m] + eps)
// ---------------------------------------------------------------------------
__global__ __launch_bounds__(256) void out_kernel(
    const float* __restrict__ qp, const float* __restrict__ kv,
    const float* __restrict__ ksum, float* __restrict__ attn)
{
    __shared__ float  kvs[4096];      // [m][v]
    __shared__ float  kss[64];
    __shared__ float4 qbuf[4][64];
    const int t = threadIdx.x, lane = t & 63, wave = t >> 6;
    const int h = blockIdx.x;
    const int n0 = blockIdx.y * 64;

    for (int i = t; i < 4096; i += 256) kvs[i] = kv[(size_t)h * 4096 + i];
    if (t < 64) kss[t] = ksum[h * 64 + t];
    __syncthreads();

    const float* qsrc = qp + (size_t)h * N_ * 64 + lane;
    float* adst = attn + h * HD_ + lane;

    for (int iter = 0; iter < 4; iter++) {
        const int n = n0 + iter * 16 + wave * 4;
        float q0 = qsrc[(size_t)(n+0) * 64];
        float q1 = qsrc[(size_t)(n+1) * 64];
        float q2 = qsrc[(size_t)(n+2) * 64];
        float q3 = qsrc[(size_t)(n+3) * 64];
        qbuf[wave][lane] = make_float4(q0, q1, q2, q3);
        float t0 = q0 * kss[lane], t1 = q1 * kss[lane];
        float t2 = q2 * kss[lane], t3 = q3 * kss[lane];
#pragma unroll
        for (int off = 32; off >= 1; off >>= 1) {
            t0 += __shfl_xor(t0, off, 64);
            t1 += __shfl_xor(t1, off, 64);
            t2 += __shfl_xor(t2, off, 64);
            t3 += __shfl_xor(t3, off, 64);
        }
        float a0 = 0.f, a1 = 0.f, a2 = 0.f, a3 = 0.f;
#pragma unroll
        for (int m = 0; m < 64; m++) {
            float kvv = kvs[m*64 + lane];     // conflict-free
            float4 q = qbuf[wave][m];         // b128 broadcast
            a0 = fmaf(q.x, kvv, a0);
            a1 = fmaf(q.y, kvv, a1);
            a2 = fmaf(q.z, kvv, a2);
            a3 = fmaf(q.w, kvv, a3);
        }
        adst[(size_t)(n+0) * D_] = a0 / (t0 + EPS_);
        adst[(size_t)(n+1) * D_] = a1 / (t1 + EPS_);
        adst[(size_t)(n+2) * D_] = a2 / (t2 + EPS_);
        adst[(size_t)(n+3) * D_] = a3 / (t3 + EPS_);
    }
}

// ---------------------------------------------------------------------------
extern "C" void kernel_launch(void* const* d_in, const int* in_sizes, int n_in,
                              void* d_out, int out_size, void* d_ws, size_t ws_size,
                              hipStream_t stream)
{
    const float* x      = (const float*)d_in[0];   // [4,4096,1024]
    const float* qkv_w  = (const float*)d_in[1];   // [3072,1024]
    const float* qkv_b  = (const float*)d_in[2];   // [3072]
    const float* proj_w = (const float*)d_in[3];   // [1024,1024]
    const float* proj_b = (const float*)d_in[4];   // [1024]
    const float* pm     = (const float*)d_in[5];   // [64,64]
    float* out = (float*)d_out;                    // [4,4096,1024] fp32
    float* ws  = (float*)d_ws;

    // workspace layout (floats), single-batch buffers (~89 MB total):
    float* qkvb   = ws;                        // 4096*3072 = 12,582,912
    float* qp     = ws + 12582912;             // 16*4096*64 = 4,194,304
    float* kp     = qp + 4194304;              // 4,194,304
    float* kvb    = kp + 4194304;              // 16*64*64 = 65,536
    float* ksum   = kvb + 65536;               // 1,024
    float* kvpart = ksum + 1024;               // 16*32*4096 = 2,097,152
    float* kspart = kvpart + 2097152;          // 16*32*64 = 32,768
    float* attn   = qkvb;                      // reuse (qkv dead after kv stage)

    for (int b = 0; b < B_; b++) {
        const float* xb = x + (size_t)b * N_ * D_;
        float* outb = out + (size_t)b * N_ * D_;

        // 1) qkvb = xb @ qkv_w^T + qkv_b    [4096 x 3072]
        dim3 g1(TD_ / 128, N_ / 128);          // (24, 32)
        gemm_bf16x2_nt_bias<<<g1, 256, 0, stream>>>(xb, qkv_w, qkv_b, qkvb, TD_, D_);

        // 2) FAVOR features for q and k
        dim3 g2(1024, 2);
        favor_features_kernel<<<g2, 256, 0, stream>>>(qkvb, pm, qp, kp);

        // 3) kv einsum + k_sum: partials then reduce (no atomics)
        dim3 g3(16, 32);
        kv_partial_kernel<<<g3, 256, 0, stream>>>(qkvb, kp, kvpart, kspart);
        kv_reduce_kernel<<<16, 256, 0, stream>>>(kvpart, kspart, kvb, ksum);

        // 4) out einsum + normalizer -> attn [4096 x 1024]
        dim3 g4(16, 64);
        out_kernel<<<g4, 256, 0, stream>>>(qp, kvb, ksum, attn);

        // 5) outb = attn @ proj_w^T + proj_b
        dim3 g5(D_ / 128, N_ / 128);           // (8, 32)
        gemm_bf16x2_nt_bias<<<g5, 256, 0, stream>>>(attn, proj_w, proj_b, outb, D_, D_);
    }
}

// Round 5
// 1078.073 us; speedup vs baseline: 2.2630x; 1.0266x over previous
//
#include <hip/hip_runtime.h>
#include <math.h>

#define B_  4
#define N_  4096
#define D_  1024
#define H_  16
#define HD_ 64
#define M_  64
#define TD_ 3072
#define EPS_ 1e-6f

typedef __attribute__((ext_vector_type(8))) short short8;
typedef __attribute__((ext_vector_type(4))) float floatx4;
typedef unsigned int uint32;
typedef unsigned short ushort;

// Split two fp32 into packed hi-bf16 pair and lo-bf16 pair.
// hi = truncate-to-bf16 (bit surgery), lo = bf16(f - hi).
// Dropped lo*lo term in the 3-MFMA product is <= 2^-16 relative.
__device__ __forceinline__ void cvt2(float f0, float f1, uint32& hp, uint32& lp)
{
    uint32 b0 = __float_as_uint(f0), b1 = __float_as_uint(f1);
    hp = (b1 & 0xFFFF0000u) | (b0 >> 16);
    float l0 = f0 - __uint_as_float(b0 & 0xFFFF0000u);
    float l1 = f1 - __uint_as_float(b1 & 0xFFFF0000u);
    lp = (__float_as_uint(l1) & 0xFFFF0000u) | (__float_as_uint(l0) >> 16);
}

// ---------------------------------------------------------------------------
// fp32[n] -> hi bf16[n], lo bf16[n].  n multiple of 2048; 8 elems/thread.
// ---------------------------------------------------------------------------
__global__ __launch_bounds__(256) void split_kernel(
    const float* __restrict__ src, ushort* __restrict__ hi,
    ushort* __restrict__ lo, int n)
{
    size_t i = ((size_t)blockIdx.x * 256 + threadIdx.x) * 8;
    if (i >= (size_t)n) return;
    float4 f0 = *(const float4*)(src + i);
    float4 f1 = *(const float4*)(src + i + 4);
    uint4 h, l;
    cvt2(f0.x, f0.y, h.x, l.x); cvt2(f0.z, f0.w, h.y, l.y);
    cvt2(f1.x, f1.y, h.z, l.z); cvt2(f1.z, f1.w, h.w, l.w);
    *(uint4*)(hi + i) = h;
    *(uint4*)(lo + i) = l;
}

// ---------------------------------------------------------------------------
// Pre-split bf16 MFMA GEMM (NT): C = A*B^T + bias, A/B given as hi/lo bf16
// (K-contiguous, stride Kx). 128x128 tile, BK=32, 2x2 waves, 4x4 16x16 frags,
// 3 MFMAs per fragment pair (hh, lh, hl). No conversion VALU in the K-loop.
// LDS rows padded to 40 ushorts (80 B): b128 frag reads are 2-way (free).
// ---------------------------------------------------------------------------
#define LDSTR 40

__global__ __launch_bounds__(256, 2) void gemm_presplit_nt_bias(
    const ushort* __restrict__ Ah, const ushort* __restrict__ Al,
    const ushort* __restrict__ Bh, const ushort* __restrict__ Bl,
    const float* __restrict__ bias, float* __restrict__ C,
    int Nx, int Kx)
{
    __shared__ __align__(16) ushort AhiS[128*LDSTR], AloS[128*LDSTR];
    __shared__ __align__(16) ushort BhiS[128*LDSTR], BloS[128*LDSTR];

    const int t    = threadIdx.x;
    const int bm   = blockIdx.y * 128, bn = blockIdx.x * 128;
    const int lane = t & 63, wave = t >> 6;
    const int wm   = wave >> 1, wn = wave & 1;
    const int l16  = lane & 15, quad = lane >> 4;
    const int r    = t >> 1;          // staging row 0..127
    const int ko   = (t & 1) * 16;    // staging k-offset 0/16 (ushorts)

    floatx4 acc[4][4];
#pragma unroll
    for (int i = 0; i < 4; i++)
#pragma unroll
        for (int j = 0; j < 4; j++) acc[i][j] = (floatx4)0.f;

    const ushort* aph = Ah + (size_t)(bm + r) * Kx + ko;
    const ushort* apl = Al + (size_t)(bm + r) * Kx + ko;
    const ushort* bph = Bh + (size_t)(bn + r) * Kx + ko;
    const ushort* bpl = Bl + (size_t)(bn + r) * Kx + ko;

    for (int k0 = 0; k0 < Kx; k0 += 32) {
        uint4 vah0 = *(const uint4*)(aph + k0);
        uint4 vah1 = *(const uint4*)(aph + k0 + 8);
        uint4 val0 = *(const uint4*)(apl + k0);
        uint4 val1 = *(const uint4*)(apl + k0 + 8);
        uint4 vbh0 = *(const uint4*)(bph + k0);
        uint4 vbh1 = *(const uint4*)(bph + k0 + 8);
        uint4 vbl0 = *(const uint4*)(bpl + k0);
        uint4 vbl1 = *(const uint4*)(bpl + k0 + 8);

        __syncthreads();   // prior iteration's fragment reads complete

        *(uint4*)&AhiS[r*LDSTR + ko]     = vah0;
        *(uint4*)&AhiS[r*LDSTR + ko + 8] = vah1;
        *(uint4*)&AloS[r*LDSTR + ko]     = val0;
        *(uint4*)&AloS[r*LDSTR + ko + 8] = val1;
        *(uint4*)&BhiS[r*LDSTR + ko]     = vbh0;
        *(uint4*)&BhiS[r*LDSTR + ko + 8] = vbh1;
        *(uint4*)&BloS[r*LDSTR + ko]     = vbl0;
        *(uint4*)&BloS[r*LDSTR + ko + 8] = vbl1;

        __syncthreads();

        short8 ah[4], al[4], bh[4], bl[4];
#pragma unroll
        for (int mi = 0; mi < 4; mi++) {
            int row = (wm*64 + mi*16 + l16) * LDSTR + quad*8;
            ah[mi] = *(const short8*)&AhiS[row];
            al[mi] = *(const short8*)&AloS[row];
        }
#pragma unroll
        for (int ni = 0; ni < 4; ni++) {
            int row = (wn*64 + ni*16 + l16) * LDSTR + quad*8;
            bh[ni] = *(const short8*)&BhiS[row];
            bl[ni] = *(const short8*)&BloS[row];
        }
#pragma unroll
        for (int mi = 0; mi < 4; mi++)
#pragma unroll
            for (int ni = 0; ni < 4; ni++) {
                floatx4 d = acc[mi][ni];
                d = __builtin_amdgcn_mfma_f32_16x16x32_bf16(ah[mi], bh[ni], d, 0, 0, 0);
                d = __builtin_amdgcn_mfma_f32_16x16x32_bf16(al[mi], bh[ni], d, 0, 0, 0);
                d = __builtin_amdgcn_mfma_f32_16x16x32_bf16(ah[mi], bl[ni], d, 0, 0, 0);
                acc[mi][ni] = d;
            }
    }

    // epilogue: C[row][col] = acc + bias[col]
    float bia[4];
#pragma unroll
    for (int ni = 0; ni < 4; ni++)
        bia[ni] = bias[bn + wn*64 + ni*16 + l16];
#pragma unroll
    for (int mi = 0; mi < 4; mi++)
#pragma unroll
        for (int rr = 0; rr < 4; rr++) {
            int row = bm + wm*64 + mi*16 + quad*4 + rr;
            float* crow = C + (size_t)row * Nx + bn + wn*64 + l16;
#pragma unroll
            for (int ni = 0; ni < 4; ni++)
                crow[ni*16] = acc[mi][ni][rr] + bia[ni];
        }
}

// ---------------------------------------------------------------------------
// FAVOR+ feature map for ONE batch:
//   feat[h,n,m] = exp(dn.proj[m] - 0.5|dn|^2 - rowmax)/8 + eps
// ---------------------------------------------------------------------------
__global__ __launch_bounds__(256) void favor_features_kernel(
    const float* __restrict__ qkvb, const float* __restrict__ proj,
    float* __restrict__ qp, float* __restrict__ kp)
{
    __shared__ float  projT[64*64];   // projT[d*64+m]
    __shared__ float4 dnbuf[4][64];   // per wave: [d] -> 4 rows' dn[d]
    const int t = threadIdx.x;
    const int wave = t >> 6, lane = t & 63;
    const int part = blockIdx.y;
    float* outp = (part == 0) ? qp : kp;

    for (int i = t; i < 4096; i += 256)
        projT[(i & 63) * 64 + (i >> 6)] = proj[i];
    __syncthreads();

    const int h = blockIdx.x >> 6;             // 64 blocks per head
    const int n0 = (blockIdx.x & 63) * 64;
    const float* src = qkvb + part * D_ + h * HD_ + lane;

    for (int iter = 0; iter < 4; iter++) {
        const int n = n0 + iter * 16 + wave * 4;
        float v0 = src[(size_t)(n+0) * TD_];
        float v1 = src[(size_t)(n+1) * TD_];
        float v2 = src[(size_t)(n+2) * TD_];
        float v3 = src[(size_t)(n+3) * TD_];
        float4 dn = make_float4(v0*0.125f, v1*0.125f, v2*0.125f, v3*0.125f);
        dnbuf[wave][lane] = dn;
        float s0 = dn.x*dn.x, s1 = dn.y*dn.y, s2 = dn.z*dn.z, s3 = dn.w*dn.w;
#pragma unroll
        for (int off = 32; off >= 1; off >>= 1) {
            s0 += __shfl_xor(s0, off, 64);
            s1 += __shfl_xor(s1, off, 64);
            s2 += __shfl_xor(s2, off, 64);
            s3 += __shfl_xor(s3, off, 64);
        }
        float c0 = -0.5f*s0, c1 = -0.5f*s1, c2 = -0.5f*s2, c3 = -0.5f*s3;
#pragma unroll
        for (int d = 0; d < 64; d++) {
            float p = projT[d*64 + lane];     // conflict-free (lanes consecutive)
            float4 q = dnbuf[wave][d];        // b128 broadcast
            c0 = fmaf(q.x, p, c0);
            c1 = fmaf(q.y, p, c1);
            c2 = fmaf(q.z, p, c2);
            c3 = fmaf(q.w, p, c3);
        }
        float m0 = c0, m1 = c1, m2 = c2, m3 = c3;
#pragma unroll
        for (int off = 32; off >= 1; off >>= 1) {
            m0 = fmaxf(m0, __shfl_xor(m0, off, 64));
            m1 = fmaxf(m1, __shfl_xor(m1, off, 64));
            m2 = fmaxf(m2, __shfl_xor(m2, off, 64));
            m3 = fmaxf(m3, __shfl_xor(m3, off, 64));
        }
        float r0 = expf(c0 - m0) * 0.125f + EPS_;
        float r1 = expf(c1 - m1) * 0.125f + EPS_;
        float r2 = expf(c2 - m2) * 0.125f + EPS_;
        float r3 = expf(c3 - m3) * 0.125f + EPS_;
        size_t orow = ((size_t)h * N_ + n) * 64 + lane;
        outp[orow]       = r0;
        outp[orow + 64]  = r1;
        outp[orow + 128] = r2;
        outp[orow + 192] = r3;
    }
}

// ---------------------------------------------------------------------------
// kv stage 1: per (h, n-chunk of 128) partial sums, no atomics.
// ---------------------------------------------------------------------------
__global__ __launch_bounds__(256) void kv_partial_kernel(
    const float* __restrict__ qkvb, const float* __restrict__ kp,
    float* __restrict__ kvpart, float* __restrict__ kspart)
{
    const int t = threadIdx.x;
    const int h = blockIdx.x;
    const int c = blockIdx.y;
    const int n0 = c * 128;
    const int m0 = (t & 15) * 4;
    const int v0 = (t >> 4) * 4;

    const float* kpsrc = kp + ((size_t)h * N_ + n0) * 64 + m0;
    const float* vsrc  = qkvb + (size_t)n0 * TD_ + 2 * D_ + h * HD_ + v0;

    float acc[4][4];
#pragma unroll
    for (int i = 0; i < 4; i++)
#pragma unroll
        for (int j = 0; j < 4; j++) acc[i][j] = 0.f;
    float ks[4] = {0.f, 0.f, 0.f, 0.f};

#pragma unroll 4
    for (int n = 0; n < 128; n++) {
        float4 kq = *(const float4*)(kpsrc + (size_t)n * 64);
        float4 vq = *(const float4*)(vsrc  + (size_t)n * TD_);
        acc[0][0] = fmaf(kq.x, vq.x, acc[0][0]);
        acc[0][1] = fmaf(kq.x, vq.y, acc[0][1]);
        acc[0][2] = fmaf(kq.x, vq.z, acc[0][2]);
        acc[0][3] = fmaf(kq.x, vq.w, acc[0][3]);
        acc[1][0] = fmaf(kq.y, vq.x, acc[1][0]);
        acc[1][1] = fmaf(kq.y, vq.y, acc[1][1]);
        acc[1][2] = fmaf(kq.y, vq.z, acc[1][2]);
        acc[1][3] = fmaf(kq.y, vq.w, acc[1][3]);
        acc[2][0] = fmaf(kq.z, vq.x, acc[2][0]);
        acc[2][1] = fmaf(kq.z, vq.y, acc[2][1]);
        acc[2][2] = fmaf(kq.z, vq.z, acc[2][2]);
        acc[2][3] = fmaf(kq.z, vq.w, acc[2][3]);
        acc[3][0] = fmaf(kq.w, vq.x, acc[3][0]);
        acc[3][1] = fmaf(kq.w, vq.y, acc[3][1]);
        acc[3][2] = fmaf(kq.w, vq.z, acc[3][2]);
        acc[3][3] = fmaf(kq.w, vq.w, acc[3][3]);
        if (v0 == 0) {
            ks[0] += kq.x; ks[1] += kq.y; ks[2] += kq.z; ks[3] += kq.w;
        }
    }

    float* kvp = kvpart + (((size_t)h * 32 + c) * 4096) + m0 * 64 + v0;
#pragma unroll
    for (int i = 0; i < 4; i++)
        *(float4*)(kvp + i * 64) = make_float4(acc[i][0], acc[i][1], acc[i][2], acc[i][3]);

    if (v0 == 0) {
        float* ksp = kspart + ((size_t)h * 32 + c) * 64 + m0;
        *(float4*)ksp = make_float4(ks[0], ks[1], ks[2], ks[3]);
    }
}

// ---------------------------------------------------------------------------
// kv stage 2: reduce 32 chunk-partials -> kv[h][4096], ksum[h][64]
// ---------------------------------------------------------------------------
__global__ __launch_bounds__(256) void kv_reduce_kernel(
    const float* __restrict__ kvpart, const float* __restrict__ kspart,
    float* __restrict__ kv, float* __restrict__ ksum)
{
    const int t = threadIdx.x;
    const int h = blockIdx.x;
    const int e0 = t * 16;

    float4 s[4];
#pragma unroll
    for (int i = 0; i < 4; i++) s[i] = make_float4(0.f, 0.f, 0.f, 0.f);
    float kss = 0.f;

    for (int c = 0; c < 32; c++) {
        const float* p = kvpart + (((size_t)h * 32 + c) * 4096) + e0;
#pragma unroll
        for (int i = 0; i < 4; i++) {
            float4 x = *(const float4*)(p + i * 4);
            s[i].x += x.x; s[i].y += x.y; s[i].z += x.z; s[i].w += x.w;
        }
        if (t < 64) kss += kspart[((size_t)h * 32 + c) * 64 + t];
    }

    float* kvo = kv + (size_t)h * 4096 + e0;
#pragma unroll
    for (int i = 0; i < 4; i++) *(float4*)(kvo + i * 4) = s[i];
    if (t < 64) ksum[h * 64 + t] = kss;
}

// ---------------------------------------------------------------------------
// out[h,n,v] = (sum_m qp*kv) / (sum_m qp*ksum + eps); split directly into
// hi/lo bf16 for the final GEMM (saves a separate split pass).
// ---------------------------------------------------------------------------
__global__ __launch_bounds__(256) void out_kernel(
    const float* __restrict__ qp, const float* __restrict__ kv,
    const float* __restrict__ ksum, ushort* __restrict__ attn_hi,
    ushort* __restrict__ attn_lo)
{
    __shared__ float  kvs[4096];      // [m][v]
    __shared__ float  kss[64];
    __shared__ float4 qbuf[4][64];
    const int t = threadIdx.x, lane = t & 63, wave = t >> 6;
    const int h = blockIdx.x;
    const int n0 = blockIdx.y * 64;

    for (int i = t; i < 4096; i += 256) kvs[i] = kv[(size_t)h * 4096 + i];
    if (t < 64) kss[t] = ksum[h * 64 + t];
    __syncthreads();

    const float* qsrc = qp + (size_t)h * N_ * 64 + lane;
    const size_t dbase = h * HD_ + lane;

    for (int iter = 0; iter < 4; iter++) {
        const int n = n0 + iter * 16 + wave * 4;
        float q0 = qsrc[(size_t)(n+0) * 64];
        float q1 = qsrc[(size_t)(n+1) * 64];
        float q2 = qsrc[(size_t)(n+2) * 64];
        float q3 = qsrc[(size_t)(n+3) * 64];
        qbuf[wave][lane] = make_float4(q0, q1, q2, q3);
        float t0 = q0 * kss[lane], t1 = q1 * kss[lane];
        float t2 = q2 * kss[lane], t3 = q3 * kss[lane];
#pragma unroll
        for (int off = 32; off >= 1; off >>= 1) {
            t0 += __shfl_xor(t0, off, 64);
            t1 += __shfl_xor(t1, off, 64);
            t2 += __shfl_xor(t2, off, 64);
            t3 += __shfl_xor(t3, off, 64);
        }
        float a0 = 0.f, a1 = 0.f, a2 = 0.f, a3 = 0.f;
#pragma unroll
        for (int m = 0; m < 64; m++) {
            float kvv = kvs[m*64 + lane];     // conflict-free
            float4 q = qbuf[wave][m];         // b128 broadcast
            a0 = fmaf(q.x, kvv, a0);
            a1 = fmaf(q.y, kvv, a1);
            a2 = fmaf(q.z, kvv, a2);
            a3 = fmaf(q.w, kvv, a3);
        }
        float r[4];
        r[0] = a0 / (t0 + EPS_); r[1] = a1 / (t1 + EPS_);
        r[2] = a2 / (t2 + EPS_); r[3] = a3 / (t3 + EPS_);
#pragma unroll
        for (int i = 0; i < 4; i++) {
            uint32 bits = __float_as_uint(r[i]);
            float lof = r[i] - __uint_as_float(bits & 0xFFFF0000u);
            size_t idx = (size_t)(n + i) * D_ + dbase;
            attn_hi[idx] = (ushort)(bits >> 16);
            attn_lo[idx] = (ushort)(__float_as_uint(lof) >> 16);
        }
    }
}

// ---------------------------------------------------------------------------
extern "C" void kernel_launch(void* const* d_in, const int* in_sizes, int n_in,
                              void* d_out, int out_size, void* d_ws, size_t ws_size,
                              hipStream_t stream)
{
    const float* x      = (const float*)d_in[0];   // [4,4096,1024]
    const float* qkv_w  = (const float*)d_in[1];   // [3072,1024]
    const float* qkv_b  = (const float*)d_in[2];   // [3072]
    const float* proj_w = (const float*)d_in[3];   // [1024,1024]
    const float* proj_b = (const float*)d_in[4];   // [1024]
    const float* pm     = (const float*)d_in[5];   // [64,64]
    float* out = (float*)d_out;                    // [4,4096,1024] fp32
    float* ws  = (float*)d_ws;

    // workspace layout (floats), ~109 MB total, with aliasing:
    float* qkvb   = ws;                        // 12,582,912 f (48 MB)
    float* qpreg  = ws + 12582912;             // 4,194,304 f: x_hi/x_lo then qp
    float* kpreg  = qpreg + 4194304;           // 4,194,304 f: kp then attn_hi/lo
    float* kvb    = kpreg + 4194304;           // 65,536
    float* ksum   = kvb + 65536;               // 1,024
    float* kvpart = ksum + 1024;               // 2,097,152
    float* kspart = kvpart + 2097152;          // 32,768
    float* wsplit = kspart + 32768;            // 4,194,304 f = split weights

    // ushort views
    ushort* xw_hi   = (ushort*)qpreg;          // 4,194,304 us (then becomes qp)
    ushort* xw_lo   = xw_hi + 4194304;
    float*  qp      = qpreg;
    float*  kp      = kpreg;
    ushort* attn_hi = (ushort*)kpreg;          // aliases kp (dead after kv stage)
    ushort* attn_lo = attn_hi + 4194304;
    ushort* qkvw_hi = (ushort*)wsplit;         // 3,145,728 us
    ushort* qkvw_lo = qkvw_hi + 3145728;
    ushort* projw_hi= qkvw_lo + 3145728;       // 1,048,576 us
    ushort* projw_lo= projw_hi + 1048576;

    // Split weights once per launch (constant across batches).
    split_kernel<<<TD_*D_/2048, 256, 0, stream>>>(qkv_w, qkvw_hi, qkvw_lo, TD_*D_);
    split_kernel<<<D_*D_/2048,  256, 0, stream>>>(proj_w, projw_hi, projw_lo, D_*D_);

    for (int b = 0; b < B_; b++) {
        const float* xb = x + (size_t)b * N_ * D_;
        float* outb = out + (size_t)b * N_ * D_;

        // 0) split x_b into hi/lo bf16 (lives in the future-qp region)
        split_kernel<<<N_*D_/2048, 256, 0, stream>>>(xb, xw_hi, xw_lo, N_*D_);

        // 1) qkvb = xb @ qkv_w^T + qkv_b    [4096 x 3072]
        dim3 g1(TD_ / 128, N_ / 128);          // (24, 32)
        gemm_presplit_nt_bias<<<g1, 256, 0, stream>>>(
            xw_hi, xw_lo, qkvw_hi, qkvw_lo, qkv_b, qkvb, TD_, D_);

        // 2) FAVOR features for q and k (qp overwrites x_hi/lo — x is dead)
        dim3 g2(1024, 2);
        favor_features_kernel<<<g2, 256, 0, stream>>>(qkvb, pm, qp, kp);

        // 3) kv einsum + k_sum: partials then reduce (no atomics)
        dim3 g3(16, 32);
        kv_partial_kernel<<<g3, 256, 0, stream>>>(qkvb, kp, kvpart, kspart);
        kv_reduce_kernel<<<16, 256, 0, stream>>>(kvpart, kspart, kvb, ksum);

        // 4) out einsum + normalizer -> attn hi/lo (overwrites kp — dead)
        dim3 g4(16, 64);
        out_kernel<<<g4, 256, 0, stream>>>(qp, kvb, ksum, attn_hi, attn_lo);

        // 5) outb = attn @ proj_w^T + proj_b
        dim3 g5(D_ / 128, N_ / 128);           // (8, 32)
        gemm_presplit_nt_bias<<<g5, 256, 0, stream>>>(
            attn_hi, attn_lo, projw_hi, projw_lo, proj_b, outb, D_, D_);
    }
}